// Round 2
// baseline (326.726 us; speedup 1.0000x reference)
//
#include <hip/hip_runtime.h>
#include <hip/hip_bf16.h>
#include <math.h>

// Problem constants
#define NN 32768
#define CC 512
#define AA 64
#define CIN 1024
#define EPSV 1e-7f

// All inputs/outputs are FLOAT32 (reference dtype).
//
// Workspace layout (floats):
//   [0,576)      query (after bias)
//   [576,1088)   erase
//   [1088,1600)  conth = W_content_hidden @ h
//   [1600,2112)  contx = W_content_input @ x
//   [2112,2128)  scalars: 2112 beta, 2113 gamma, 2114 alpha, 2115 qnorm,
//                         2116 mx, 2117 invZ, 2118 S2
//   [2128,34896)     s[32768] (pre-softmax logits)
//   [34896,559184)   part_m[1024][512]  (elem-major partials: e*512+blk)
//   [559184,567376)  part_a[64][128]
// Total 567376 floats = 2.27 MB

// ---------------- K1: all GEMVs + scalar dots -----------------------------
// grid 2115 blocks x 256 thr. Block r:
//   r<576: W_query row | r<1088: W_erase row | r<1600: W_content_hidden row
//   r<2112: W_content_input row (len 1024 over x)
//   r=2112: u_sharpen.h  r=2113: u_lru.h  r=2114: u_content_alpha.[h;x]
__global__ __launch_bounds__(256) void k1_gemv(
    const float* __restrict__ h, const float* __restrict__ x,
    const float* __restrict__ Wq, const float* __restrict__ bq,
    const float* __restrict__ ush, const float* __restrict__ ulr,
    const float* __restrict__ Wer, const float* __restrict__ ber,
    const float* __restrict__ Wch, const float* __restrict__ Wci,
    const float* __restrict__ uca,
    float* __restrict__ ws)
{
    __shared__ float red[256];
    const int r = blockIdx.x, tid = threadIdx.x;
    float sum = 0.f;
    if (r < 1600 || r >= 2112) {
        const float* vec;
        if (r < 576)       vec = Wq  + (size_t)r * NN;
        else if (r < 1088) vec = Wer + (size_t)(r - 576) * NN;
        else if (r < 1600) vec = Wch + (size_t)(r - 1088) * NN;
        else if (r == 2112) vec = ush;
        else if (r == 2113) vec = ulr;
        else                vec = uca;
        for (int j = tid * 4; j < NN; j += 1024) {
            float4 a = *reinterpret_cast<const float4*>(vec + j);
            float4 b = *reinterpret_cast<const float4*>(h + j);
            sum += a.x * b.x + a.y * b.y + a.z * b.z + a.w * b.w;
        }
        if (r == 2114) { // tail of u_content_alpha over x
            float4 a = *reinterpret_cast<const float4*>(uca + NN + tid * 4);
            float4 b = *reinterpret_cast<const float4*>(x + tid * 4);
            sum += a.x * b.x + a.y * b.y + a.z * b.z + a.w * b.w;
        }
    } else { // W_content_input rows, len 1024 over x
        const float* vec = Wci + (size_t)(r - 1600) * CIN;
        float4 a = *reinterpret_cast<const float4*>(vec + tid * 4);
        float4 b = *reinterpret_cast<const float4*>(x + tid * 4);
        sum += a.x * b.x + a.y * b.y + a.z * b.z + a.w * b.w;
    }
    red[tid] = sum; __syncthreads();
    for (int st = 128; st > 0; st >>= 1) {
        if (tid < st) red[tid] += red[tid + st];
        __syncthreads();
    }
    if (tid == 0) {
        float v = red[0];
        if (r < 576)       v += bq[r];
        else if (r < 1088) v += ber[r - 576];
        ws[r] = v;
    }
}

// ---------------- K1b: qnorm + scalar nonlinearities ----------------------
__global__ __launch_bounds__(256) void k1b_scalars(
    const float* __restrict__ bsh, const float* __restrict__ blr,
    const float* __restrict__ bca, float* __restrict__ ws)
{
    __shared__ float red[256];
    const int tid = threadIdx.x;
    float s = 0.f;
    for (int j = tid; j < 576; j += 256) { float q = ws[j]; s += q * q; }
    red[tid] = s; __syncthreads();
    for (int st = 128; st > 0; st >>= 1) {
        if (tid < st) red[tid] += red[tid + st];
        __syncthreads();
    }
    if (tid == 0) {
        float qn = fmaxf(sqrtf(red[0]), EPSV);
        float bp = ws[2112] + bsh[0];
        float beta = (bp > 20.f ? bp : log1pf(expf(bp))) + 1.0f;
        float gp = ws[2113] + blr[0];
        float gamma = 1.f / (1.f + expf(-gp));
        float alpha = ws[2114] + bca[0];
        ws[2112] = beta; ws[2113] = gamma; ws[2114] = alpha; ws[2115] = qn;
    }
}

// ---------------- K2: per-row norm + dot vs q -> logits s ------------------
// grid 2048 x 256 (4 waves), one wave per row, 4 rows per wave.
__global__ __launch_bounds__(256) void k2_sim(
    const float* __restrict__ Mm, const float* __restrict__ Ad,
    const float* __restrict__ ema, const float* __restrict__ ws,
    float* __restrict__ ws_s)
{
    const int tid = threadIdx.x, wave = tid >> 6, lane = tid & 63;
    const float beta = ws[2112], gamma = ws[2113], qn = ws[2115];
    const float ql = ws[lane];
    float4 qa = *reinterpret_cast<const float4*>(ws + 64 + lane * 8);
    float4 qb = *reinterpret_cast<const float4*>(ws + 68 + lane * 8);
    float qm[8] = {qa.x, qa.y, qa.z, qa.w, qb.x, qb.y, qb.z, qb.w};
    #pragma unroll
    for (int j = 0; j < 4; ++j) {
        const int i = blockIdx.x * 16 + wave * 4 + j;
        float a = Ad[(size_t)i * AA + lane];
        float4 m0 = *reinterpret_cast<const float4*>(Mm + (size_t)i * CC + lane * 8);
        float4 m1 = *reinterpret_cast<const float4*>(Mm + (size_t)i * CC + lane * 8 + 4);
        float mm[8] = {m0.x, m0.y, m0.z, m0.w, m1.x, m1.y, m1.z, m1.w};
        float dot = a * ql, nn = a * a;
        #pragma unroll
        for (int k = 0; k < 8; ++k) { float f = mm[k]; dot += f * qm[k]; nn += f * f; }
        #pragma unroll
        for (int off = 32; off >= 1; off >>= 1) {
            dot += __shfl_xor(dot, off);
            nn  += __shfl_xor(nn, off);
        }
        if (lane == 0) {
            float mn = fmaxf(sqrtf(nn), EPSV);
            ws_s[i] = beta * (dot / (mn * qn)) - gamma * ema[i];
        }
    }
}

// ---------------- K3: softmax stats (max, 1/Z, S2=sum addr^2) -------------
__global__ __launch_bounds__(1024) void k3_softmax(float* __restrict__ ws)
{
    const float* s = ws + 2128;
    __shared__ float lmx[16], lz[16], ls2[16], bc[1];
    const int tid = threadIdx.x, lane = tid & 63, wid = tid >> 6;
    float v[32];
    float mx = -1e30f;
    #pragma unroll
    for (int j = 0; j < 32; ++j) { v[j] = s[tid + 1024 * j]; mx = fmaxf(mx, v[j]); }
    #pragma unroll
    for (int off = 32; off >= 1; off >>= 1) mx = fmaxf(mx, __shfl_xor(mx, off));
    if (lane == 0) lmx[wid] = mx;
    __syncthreads();
    if (tid == 0) { float m = lmx[0]; for (int k = 1; k < 16; ++k) m = fmaxf(m, lmx[k]); bc[0] = m; }
    __syncthreads();
    mx = bc[0];
    float z = 0.f, s2 = 0.f;
    #pragma unroll
    for (int j = 0; j < 32; ++j) { float e = expf(v[j] - mx); z += e; s2 += e * e; }
    #pragma unroll
    for (int off = 32; off >= 1; off >>= 1) { z += __shfl_xor(z, off); s2 += __shfl_xor(s2, off); }
    if (lane == 0) { lz[wid] = z; ls2[wid] = s2; }
    __syncthreads();
    if (tid == 0) {
        float Z = 0.f, S = 0.f;
        for (int k = 0; k < 16; ++k) { Z += lz[k]; S += ls2[k]; }
        ws[2116] = mx; ws[2117] = 1.f / Z; ws[2118] = S / (Z * Z);
    }
}

// ---------------- K4: weighted column sums of M (w1, w1^2) + addresses ----
// grid 640: blocks [0,512) -> M part (64 rows each); [512,640) -> A part (256 rows each)
__global__ __launch_bounds__(256) void k4_acc(
    const float* __restrict__ Mm, const float* __restrict__ Ad,
    const float* __restrict__ ws, float* __restrict__ pm, float* __restrict__ pa)
{
    __shared__ float lds[4][1024];
    const int b = blockIdx.x, tid = threadIdx.x, wave = tid >> 6, lane = tid & 63;
    const float* s = ws + 2128;
    const float mx = ws[2116], invZ = ws[2117];
    if (b < 512) {
        float a1[8] = {0,0,0,0,0,0,0,0};
        float a2[8] = {0,0,0,0,0,0,0,0};
        for (int j = 0; j < 16; ++j) {
            const int i = b * 64 + j * 4 + wave;
            float w1 = expf(s[i] - mx) * invZ;
            float w2 = w1 * w1;
            float4 m0 = *reinterpret_cast<const float4*>(Mm + (size_t)i * CC + lane * 8);
            float4 m1 = *reinterpret_cast<const float4*>(Mm + (size_t)i * CC + lane * 8 + 4);
            float mm[8] = {m0.x, m0.y, m0.z, m0.w, m1.x, m1.y, m1.z, m1.w};
            #pragma unroll
            for (int k = 0; k < 8; ++k) { float f = mm[k]; a1[k] += w1 * f; a2[k] += w2 * f; }
        }
        #pragma unroll
        for (int k = 0; k < 8; ++k) {
            lds[wave][lane * 8 + k] = a1[k];
            lds[wave][512 + lane * 8 + k] = a2[k];
        }
        __syncthreads();
        for (int e = tid; e < 1024; e += 256) {
            float v = lds[0][e] + lds[1][e] + lds[2][e] + lds[3][e];
            pm[(size_t)e * 512 + b] = v;
        }
    } else {
        const int bb = b - 512;
        float acc = 0.f;
        for (int j = 0; j < 64; ++j) {
            const int i = bb * 256 + j * 4 + wave;
            float w1 = expf(s[i] - mx) * invZ;
            acc += w1 * Ad[(size_t)i * AA + lane];
        }
        lds[wave][lane] = acc;
        __syncthreads();
        if (tid < 64) {
            float v = lds[0][tid] + lds[1][tid] + lds[2][tid] + lds[3][tid];
            pa[tid * 128 + bb] = v;
        }
    }
}

// ---------------- K5: reduce partials + epilogue --------------------------
// grid 576: block b<64 -> out[b] from pa; else c=b-64 -> out[64+c]
__global__ __launch_bounds__(256) void k5_final(
    const float* __restrict__ ws, const float* __restrict__ pm,
    const float* __restrict__ pa, float* __restrict__ out)
{
    __shared__ float red[256];
    const int b = blockIdx.x, tid = threadIdx.x;
    if (b < 64) {
        float v = (tid < 128) ? pa[b * 128 + tid] : 0.f;
        red[tid] = v; __syncthreads();
        for (int st = 128; st > 0; st >>= 1) {
            if (tid < st) red[tid] += red[tid + st];
            __syncthreads();
        }
        if (tid == 0) out[b] = red[0];
    } else {
        const int c = b - 64;
        float v1 = pm[(size_t)c * 512 + tid] + pm[(size_t)c * 512 + tid + 256];
        float v2 = pm[(size_t)(512 + c) * 512 + tid] + pm[(size_t)(512 + c) * 512 + tid + 256];
        red[tid] = v1; __syncthreads();
        for (int st = 128; st > 0; st >>= 1) {
            if (tid < st) red[tid] += red[tid + st];
            __syncthreads();
        }
        float s1 = red[0];
        __syncthreads();
        red[tid] = v2; __syncthreads();
        for (int st = 128; st > 0; st >>= 1) {
            if (tid < st) red[tid] += red[tid + st];
            __syncthreads();
        }
        if (tid == 0) {
            float s2v = red[0];
            float er = ws[576 + c], ch = ws[1088 + c], cx = ws[1600 + c];
            float alpha = ws[2114], S2 = ws[2118];
            float cand = fmaxf(ch + alpha * cx, 0.f);
            out[64 + c] = s1 - er * s2v + S2 * cand;
        }
    }
}

extern "C" void kernel_launch(void* const* d_in, const int* in_sizes, int n_in,
                              void* d_out, int out_size, void* d_ws, size_t ws_size,
                              hipStream_t stream)
{
    const float* h   = (const float*)d_in[0];
    const float* x   = (const float*)d_in[1];
    const float* Mm  = (const float*)d_in[2];
    const float* Ad  = (const float*)d_in[3];
    const float* ema = (const float*)d_in[4];
    const float* Wq  = (const float*)d_in[5];
    const float* bq  = (const float*)d_in[6];
    const float* ush = (const float*)d_in[7];
    const float* bsh = (const float*)d_in[8];
    const float* ulr = (const float*)d_in[9];
    const float* blr = (const float*)d_in[10];
    const float* Wer = (const float*)d_in[11];
    const float* ber = (const float*)d_in[12];
    const float* Wch = (const float*)d_in[13];
    const float* Wci = (const float*)d_in[14];
    const float* uca = (const float*)d_in[15];
    const float* bca = (const float*)d_in[16];

    float* ws   = (float*)d_ws;
    float* ws_s = ws + 2128;
    float* pm   = ws + 34896;
    float* pa   = ws + 559184;
    float* out  = (float*)d_out;

    hipLaunchKernelGGL(k1_gemv,    dim3(2115), dim3(256),  0, stream,
                       h, x, Wq, bq, ush, ulr, Wer, ber, Wch, Wci, uca, ws);
    hipLaunchKernelGGL(k1b_scalars, dim3(1),   dim3(256),  0, stream, bsh, blr, bca, ws);
    hipLaunchKernelGGL(k2_sim,     dim3(2048), dim3(256),  0, stream, Mm, Ad, ema, ws, ws_s);
    hipLaunchKernelGGL(k3_softmax, dim3(1),    dim3(1024), 0, stream, ws);
    hipLaunchKernelGGL(k4_acc,     dim3(640),  dim3(256),  0, stream, Mm, Ad, ws, pm, pa);
    hipLaunchKernelGGL(k5_final,   dim3(576),  dim3(256),  0, stream, ws, pm, pa, out);
}